// Round 16
// baseline (25.342 us; speedup 1.0000x reference)
//
#include <hip/hip_runtime.h>

// SHToGridDensity: density[row][g] = sum_{lm,r} coeffs[row][lm][r]*Y[lm][g]*R[r][g]
// row in 0..255, g in 0..35936. Inputs f32; OUTPUT f32 (r9-verified).
//
// GEMM D[256][G] = A[256][K=400] x B[400][G] on mfma_f32_32x32x16_bf16.
// K = 25 lm-steps x 16 r: each MFMA consumes exactly one lm (no pad).
// Per-lane operand map (BOTH operands, shared bijection — r12..r15 on-device
// verified, absmax 0.125):
//   A: row = l&31 (+32*mt), elem j at k-local = (l>>5)*8 + j
//   B: col = l&31, same k-local map, in-register:
//      elem j = Y[lm][g] * R[(l>>5)*8+j][g], RNE via v_cvt_pk_bf16_f32
// D: col = l&31, row = (reg&3) + 8*(reg>>2) + 4*(l>>5)  [m74/m101 HW-verified]
//
// r16 (r15 post-mortem: LDS port ~8.8us from 8x intra-block A re-read +
// coarse-block dispatch tail): wave = 64 cols x 1 m-tile -> 1 ds_read_b128
// feeds 2 MFMAs (LDS/MFMA halved); block = 4 waves, 256 cols, 25.6 KB LDS;
// grid = 141 x 8 = 1128 fine blocks (~2us) -> HW backfill balances.
// Staging/fragments/D-layout bit-identical to r15.

#define G_TOTAL 35937
#define N_ROWS  256

typedef __attribute__((ext_vector_type(8))) short bf16x8;
typedef __attribute__((ext_vector_type(16))) float f32x16;

__constant__ int c_lmFlat[25] = {4, 12,13,14, 20,21,22,23,24,
                                 28,29,30,31,32,33,34,
                                 36,37,38,39,40,41,42,43,44};

// Block = 256 threads = 4 waves. blockIdx.y = m-tile (32 rows); wave w ->
// cols [gx*256 + w*64, +64) as two 32-col slabs. grid = (141, 8).
__global__ __launch_bounds__(256, 3) void sh_fused(
        const float* __restrict__ coeffs,
        const float* __restrict__ Y,
        const float* __restrict__ Rb,
        float* __restrict__ out) {
    __shared__ uint4 Alds[25 * 64];            // 25600 B: [ks][lane]
    const int tx = threadIdx.x;
    const int l  = tx & 63;
    const int w  = tx >> 6;          // 0..3
    const int cl = l & 31;
    const int kg = l >> 5;           // 0..1 k-group (r-half)

    const int mt = blockIdx.y;       // m-tile: rows [mt*32, +32)
    const int g0 = blockIdx.x * 256 + w * 64 + cl;   // slab 0
    const int g1 = g0 + 32;                          // slab 1
    const int gc0 = g0 < G_TOTAL ? g0 : G_TOTAL - 1;
    const int gc1 = g1 < G_TOTAL ? g1 : G_TOTAL - 1;

    // ---- A stage: coeffs rows [mt*32,+32) x 25 lm-slices -> RNE bf16 LDS ----
    // chunk c (0..799): ks = c>>5, r32 = c&31. 16 f32 at
    // coeffs[(mt*32+r32)*720 + lmFlat[ks]*16] -> 8 cvt_pk -> 2 ds_write_b128.
#pragma unroll
    for (int i = 0; i < 4; ++i) {
        int c = tx + i * 256;
        if (c < 800) {
            int ks  = c >> 5;
            int r32 = c & 31;
            const float4* src = (const float4*)(coeffs + (mt * 32 + r32) * 720
                                                + c_lmFlat[ks] * 16);
            float4 f0 = src[0], f1 = src[1], f2 = src[2], f3 = src[3];
            unsigned u0, u1, u2, u3, u4, u5, u6, u7;
            asm("v_cvt_pk_bf16_f32 %0, %1, %2" : "=v"(u0) : "v"(f0.x), "v"(f0.y));
            asm("v_cvt_pk_bf16_f32 %0, %1, %2" : "=v"(u1) : "v"(f0.z), "v"(f0.w));
            asm("v_cvt_pk_bf16_f32 %0, %1, %2" : "=v"(u2) : "v"(f1.x), "v"(f1.y));
            asm("v_cvt_pk_bf16_f32 %0, %1, %2" : "=v"(u3) : "v"(f1.z), "v"(f1.w));
            asm("v_cvt_pk_bf16_f32 %0, %1, %2" : "=v"(u4) : "v"(f2.x), "v"(f2.y));
            asm("v_cvt_pk_bf16_f32 %0, %1, %2" : "=v"(u5) : "v"(f2.z), "v"(f2.w));
            asm("v_cvt_pk_bf16_f32 %0, %1, %2" : "=v"(u6) : "v"(f3.x), "v"(f3.y));
            asm("v_cvt_pk_bf16_f32 %0, %1, %2" : "=v"(u7) : "v"(f3.z), "v"(f3.w));
            Alds[ks * 64 + r32]      = make_uint4(u0, u1, u2, u3);  // kg=0 (r 0..7)
            Alds[ks * 64 + 32 + r32] = make_uint4(u4, u5, u6, u7);  // kg=1 (r 8..15)
        }
    }

    // ---- per-lane B-operand state for both slabs (overlaps staging) ----
    constexpr int lmFlat[25] = {4, 12,13,14, 20,21,22,23,24,
                                28,29,30,31,32,33,34,
                                36,37,38,39,40,41,42,43,44};
    float YA[25], YB[25];
#pragma unroll
    for (int i = 0; i < 25; ++i) {
        YA[i] = Y[lmFlat[i] * G_TOTAL + gc0];
        YB[i] = Y[lmFlat[i] * G_TOTAL + gc1];
    }
    float RA[8], RB[8];
#pragma unroll
    for (int j = 0; j < 8; ++j) {
        RA[j] = Rb[(kg * 8 + j) * G_TOTAL + gc0];
        RB[j] = Rb[(kg * 8 + j) * G_TOTAL + gc1];
    }

    f32x16 acc0, acc1;
#pragma unroll
    for (int q = 0; q < 16; ++q) { acc0[q] = 0.0f; acc1[q] = 0.0f; }

    __syncthreads();

    // ---- K-loop: 25 steps; 1 ds_read_b128 feeds 2 MFMAs (2 col-slabs) ----
    const bf16x8* __restrict__ Al = (const bf16x8*)Alds;
#pragma unroll
    for (int ks = 0; ks < 25; ++ks) {
        const float y0 = YA[ks];
        const float y1 = YB[ks];
        union { unsigned int u[4]; bf16x8 v; } fb0, fb1;
#pragma unroll
        for (int p = 0; p < 4; ++p) {
            float a_lo = y0 * RA[2 * p], a_hi = y0 * RA[2 * p + 1];
            float b_lo = y1 * RB[2 * p], b_hi = y1 * RB[2 * p + 1];
            unsigned ra, rb;
            asm("v_cvt_pk_bf16_f32 %0, %1, %2" : "=v"(ra) : "v"(a_lo), "v"(a_hi));
            asm("v_cvt_pk_bf16_f32 %0, %1, %2" : "=v"(rb) : "v"(b_lo), "v"(b_hi));
            fb0.u[p] = ra;
            fb1.u[p] = rb;
        }
        bf16x8 a = Al[ks * 64 + l];
        acc0 = __builtin_amdgcn_mfma_f32_32x32x16_bf16(a, fb0.v, acc0, 0, 0, 0);
        acc1 = __builtin_amdgcn_mfma_f32_32x32x16_bf16(a, fb1.v, acc1, 0, 0, 0);
    }

    // ---- epilogue: row = mt*32 + (reg&3) + 8*(reg>>2) + 4*kg ----
    const int rbase = mt * 32 + 4 * kg;
    if (g0 < G_TOTAL) {
#pragma unroll
        for (int reg = 0; reg < 16; ++reg) {
            int ro = (reg & 3) + 8 * (reg >> 2);
            out[(rbase + ro) * G_TOTAL + g0] = acc0[reg];
        }
    }
    if (g1 < G_TOTAL) {
#pragma unroll
        for (int reg = 0; reg < 16; ++reg) {
            int ro = (reg & 3) + 8 * (reg >> 2);
            out[(rbase + ro) * G_TOTAL + g1] = acc1[reg];
        }
    }
}

extern "C" void kernel_launch(void* const* d_in, const int* in_sizes, int n_in,
                              void* d_out, int out_size, void* d_ws, size_t ws_size,
                              hipStream_t stream) {
    // pointer identification by element count (robust to dict-order changes)
    const float *pC = nullptr, *pY = nullptr, *pR = nullptr;
    if (n_in >= 3) {
        for (int i = 0; i < 3; ++i) {
            if      (in_sizes[i] == 256 * 720)    pC = (const float*)d_in[i];
            else if (in_sizes[i] == 45 * G_TOTAL) pY = (const float*)d_in[i];
            else if (in_sizes[i] == 16 * G_TOTAL) pR = (const float*)d_in[i];
        }
    }
    if (!pC || !pY || !pR) {
        pC = (const float*)d_in[0];
        pY = (const float*)d_in[1];
        pR = (const float*)d_in[2];
    }

    float* out = (float*)d_out;   // f32 output (r9-verified)

    dim3 grid(141, 8);
    sh_fused<<<grid, 256, 0, stream>>>(pC, pY, pR, out);

    (void)d_ws; (void)ws_size; (void)out_size; (void)n_in;
}